// Round 4
// baseline (401.528 us; speedup 1.0000x reference)
//
#include <hip/hip_runtime.h>

// Viterbi detector, bit-exact vs f32 reference.
// Lane-relabeled trellis: lane l holds state pi_phi(l), phase phi = t&3.
// Labelings are GF(2)-linear, chosen so the ACS partner exchange is a
// single-DPP pattern at EVERY phase: masks (8, 2, 1, 15) =
// row_ror:8 / quad_perm[2,3,0,1] / quad_perm[1,0,3,2] / row_mirror.
//   pi_0: s = (l2, l2^l0, l2^l1, l3^l2)   (bits s0..s3)
//   pi_1: s = (l3^l2, l2, l2^l0, l2^l1)
//   pi_2: s = (l2^l1, l3^l2, l2, l2^l0)
//   pi_3: s = (l2^l0, l2^l1, l3^l2, l2)
// K1 serial forward (fused v_min_f32_dpp chain, 2-block-deep register
// prefetch, __launch_bounds__(64,1) so the 128-VGPR queue actually fits),
// checkpoints (pi_0-permuted) every 64 steps. K2 parallel replay ->
// per-lane decision bits. K3 per-chunk traceback maps. K4 compose.
// K5 emit bits as floats.

#define DEV static __device__ __forceinline__

static constexpr int T_OUT = 16384;   // output bits per seq
static constexpr int TT    = 16388;   // T + MEM steps
static constexpr int BB    = 256;     // batch
static constexpr int CHUNK = 64;
static constexpr int NFULL = 256;     // full 64-step chunks
static constexpr int NC    = 257;     // + 4-step tail chunk

// inverse labelings, nibble-packed: lane = (IPI_TAB[phi] >> (4*s)) & 15
static constexpr unsigned long long IPI_TAB[4] = {
  0x4b5a6978c3d2e1f0ULL,   // pi_0^-1
  0x4cb35da26e917f80ULL,   // pi_1^-1
  0x46ceb93157dfa820ULL,   // pi_2^-1
  0x4567cdefba983210ULL,   // pi_3^-1
};

DEV int pi_of(int phi, int l){
  int l0=l&1, l1=(l>>1)&1, l2=(l>>2)&1, l3=(l>>3)&1;
  switch(phi & 3){
    case 0:  return (l2)      | ((l2^l0)<<1) | ((l2^l1)<<2) | ((l3^l2)<<3);
    case 1:  return (l3^l2)   | ((l2)<<1)    | ((l2^l0)<<2) | ((l2^l1)<<3);
    case 2:  return (l2^l1)   | ((l3^l2)<<1) | ((l2)<<2)    | ((l2^l0)<<3);
    default: return (l2^l0)   | ((l2^l1)<<1) | ((l3^l2)<<2) | ((l2)<<3);
  }
}

template<int CTRL>
DEV float dppmov(float x){
  return __int_as_float(__builtin_amdgcn_update_dpp(0, __float_as_int(x), CTRL, 0xF, 0xF, true));
}

// partner exchange per phase: masks 8, 2, 1, 15 (all single DPP)
template<int PH>
DEV float partner_of(float p){
  if constexpr (PH == 0) return dppmov<0x128>(p);   // row_ror:8      -> ^8
  else if constexpr (PH == 1) return dppmov<0x4E>(p);    // quad[2,3,0,1] -> ^2
  else if constexpr (PH == 2) return dppmov<0xB1>(p);    // quad[1,0,3,2] -> ^1
  else return dppmov<0x140>(p);                          // row_mirror    -> ^15
}

// expected[s] = sum_j (1-2*bit_j(s)) * h[j], sequential f32 accumulation
DEV float exp_of_state(int s, float h0, float h1, float h2, float h3){
  float e =            ((s     ) & 1) ? -h0 : h0;
  e = __fadd_rn(e, (((s >> 1)) & 1) ? -h1 : h1);
  e = __fadd_rn(e, (((s >> 2)) & 1) ? -h2 : h2);
  e = __fadd_rn(e, (((s >> 3)) & 1) ? -h3 : h3);
  return e;
}

// one ACS step, fused DPP-min chain: p = min(p, dpp(p)) + (y-E)^2
// s_nop 1 guards the (VALU writes p) -> (DPP reads p) hazard.
template<int PH>
DEV void vstep_fast(float& p, float yv, float E){
  float d    = __fsub_rn(yv, E);
  float cost = __fmul_rn(d, d);
  float mn;
  if constexpr (PH == 0)
    asm("s_nop 1\n\tv_min_f32_dpp %0, %1, %2 row_ror:8 row_mask:0xf bank_mask:0xf"
        : "=&v"(mn) : "v"(p), "v"(p));
  else if constexpr (PH == 1)
    asm("s_nop 1\n\tv_min_f32_dpp %0, %1, %2 quad_perm:[2,3,0,1] row_mask:0xf bank_mask:0xf"
        : "=&v"(mn) : "v"(p), "v"(p));
  else if constexpr (PH == 2)
    asm("s_nop 1\n\tv_min_f32_dpp %0, %1, %2 quad_perm:[1,0,3,2] row_mask:0xf bank_mask:0xf"
        : "=&v"(mn) : "v"(p), "v"(p));
  else
    asm("s_nop 1\n\tv_min_f32_dpp %0, %1, %2 row_mirror row_mask:0xf bank_mask:0xf"
        : "=&v"(mn) : "v"(p), "v"(p));
  p = __fadd_rn(mn, cost);
}

// ---------------- K1: serial forward, checkpoints only ----------------
// (64,1): min-waves-per-EU = 1 -> VGPR budget up to 512, so the 2-block
// float4 prefetch queue (128 VGPRs) stays in registers at full distance.
__global__ __launch_bounds__(64, 1) void k_forward(const float* __restrict__ y,
                                                   const float* __restrict__ h,
                                                   float* __restrict__ ckpt){
  const int lane = threadIdx.x & 63;
  const int l16  = lane & 15;
  const int seq  = blockIdx.x * 4 + (lane >> 4);
  const float h0 = h[0], h1 = h[1], h2 = h[2], h3 = h[3];
  const float EA = exp_of_state(pi_of(1,l16), h0,h1,h2,h3);
  const float EB = exp_of_state(pi_of(2,l16), h0,h1,h2,h3);
  const float EC = exp_of_state(pi_of(3,l16), h0,h1,h2,h3);
  const float ED = exp_of_state(pi_of(0,l16), h0,h1,h2,h3);
  const int   st0 = pi_of(0, l16);
  const float* yrow = y + (size_t)seq * TT;

  // two-block-deep register prefetch (static indexing only)
  float4 qA[16], qB[16];
  #pragma unroll
  for (int g = 0; g < 16; ++g) qA[g] = *(const float4*)(yrow + 4*g);
  #pragma unroll
  for (int g = 0; g < 16; ++g) qB[g] = *(const float4*)(yrow + CHUNK + 4*g);

  float p = 0.0f;                     // in0 = zeros
  for (int b = 0; b < NFULL; b += 2){
    {
      const int nb = (b + 2 < NFULL) ? b + 2 : NFULL - 1;
      const float* yn = yrow + nb * CHUNK;
      #pragma unroll
      for (int g = 0; g < 16; ++g){
        float4 yv = qA[g];
        qA[g] = *(const float4*)(yn + 4*g);
        vstep_fast<0>(p, yv.x, EA);
        vstep_fast<1>(p, yv.y, EB);
        vstep_fast<2>(p, yv.z, EC);
        vstep_fast<3>(p, yv.w, ED);
      }
      ckpt[((size_t)b * BB + seq) * 16 + st0] = p;
    }
    {
      const int nb = (b + 3 < NFULL) ? b + 3 : NFULL - 1;
      const float* yn = yrow + nb * CHUNK;
      #pragma unroll
      for (int g = 0; g < 16; ++g){
        float4 yv = qB[g];
        qB[g] = *(const float4*)(yn + 4*g);
        vstep_fast<0>(p, yv.x, EA);
        vstep_fast<1>(p, yv.y, EB);
        vstep_fast<2>(p, yv.z, EC);
        vstep_fast<3>(p, yv.w, ED);
      }
      ckpt[((size_t)(b + 1) * BB + seq) * 16 + st0] = p;
    }
  }
}

// ---------------- K2: parallel chunk replay -> per-lane decision bits ----------
// role = (in-state bit3) per phase; decision d = strict (cand_b1 < cand_b0).
template<int PH>
DEV unsigned rstep(float& p, float yv, float E, bool role){
  float partner = partner_of<PH>(p);
  float c1 = role ? p : partner;
  float c0 = role ? partner : p;
  unsigned d = (c1 < c0) ? 1u : 0u;
  float mn = fminf(p, partner);
  float dd = __fsub_rn(yv, E);
  p = __fadd_rn(mn, __fmul_rn(dd, dd));
  return d;
}

__global__ __launch_bounds__(256) void k_replay(const float* __restrict__ y,
                                                const float* __restrict__ h,
                                                const float* __restrict__ ckpt,
                                                unsigned long long* __restrict__ dec){
  const int gt   = blockIdx.x * 256 + threadIdx.x;
  const int pair = gt >> 4;              // c*256 + seq
  const int l16  = gt & 15;
  const int c    = pair >> 8;
  const int seq  = pair & 255;
  const float h0 = h[0], h1 = h[1], h2 = h[2], h3 = h[3];
  const float EA = exp_of_state(pi_of(1,l16), h0,h1,h2,h3);
  const float EB = exp_of_state(pi_of(2,l16), h0,h1,h2,h3);
  const float EC = exp_of_state(pi_of(3,l16), h0,h1,h2,h3);
  const float ED = exp_of_state(pi_of(0,l16), h0,h1,h2,h3);
  const bool r0 = (((l16>>3) ^ (l16>>2)) & 1) != 0;   // bit3 of pi_0(l)
  const bool r1 = (((l16>>2) ^ (l16>>1)) & 1) != 0;   // bit3 of pi_1(l)
  const bool r2 = (((l16>>2) ^  l16    ) & 1) != 0;   // bit3 of pi_2(l)
  const bool r3 = (( l16>>2)             & 1) != 0;   // bit3 of pi_3(l)
  const int  st0 = pi_of(0, l16);

  float p = (c == 0) ? 0.0f : ckpt[((size_t)(c - 1) * BB + seq) * 16 + st0];
  const float* yc = y + (size_t)seq * TT + c * CHUNK;
  unsigned lo = 0, hi = 0;

  if (c < NFULL){
    #pragma unroll
    for (int g = 0; g < 16; ++g){
      float4 yv = *(const float4*)(yc + 4*g);
      unsigned d0 = rstep<0>(p, yv.x, EA, r0);
      unsigned d1 = rstep<1>(p, yv.y, EB, r1);
      unsigned d2 = rstep<2>(p, yv.z, EC, r2);
      unsigned d3 = rstep<3>(p, yv.w, ED, r3);
      const int t = 4 * g;
      if (t < 32) lo |= (d0 << t) | (d1 << (t+1)) | (d2 << (t+2)) | (d3 << (t+3));
      else        hi |= (d0 << (t-32)) | (d1 << (t-31)) | (d2 << (t-30)) | (d3 << (t-29));
    }
  } else {
    float4 yv = *(const float4*)(yc);
    unsigned d0 = rstep<0>(p, yv.x, EA, r0);
    unsigned d1 = rstep<1>(p, yv.y, EB, r1);
    unsigned d2 = rstep<2>(p, yv.z, EC, r2);
    unsigned d3 = rstep<3>(p, yv.w, ED, r3);
    lo = d0 | (d1 << 1) | (d2 << 2) | (d3 << 3);
  }
  dec[(size_t)pair * 16 + l16] = ((unsigned long long)hi << 32) | lo;
}

// ---------------- K3: per-chunk 16-hypothesis traceback -> maps ----------------
__global__ __launch_bounds__(256) void k_maps(const unsigned long long* __restrict__ dec,
                                              unsigned char* __restrict__ map){
  const int gt   = blockIdx.x * 256 + threadIdx.x;
  const int pair = gt >> 4;
  const int e    = gt & 15;        // end-state hypothesis; also this lane's word index
  const int c    = pair >> 8;
  const unsigned long long w = dec[(size_t)pair * 16 + e];
  const unsigned wlo = (unsigned)w, whi = (unsigned)(w >> 32);
  const int base = (threadIdx.x & 63) & 48;
  int s = e;
  if (c < NFULL){
    #pragma unroll
    for (int j = 63; j >= 0; --j){
      int l = (int)((IPI_TAB[(j + 1) & 3] >> (4 * s)) & 15);
      unsigned hw = __shfl((j >= 32) ? whi : wlo, base + l);
      int b = (hw >> (j & 31)) & 1;
      s = (s >> 1) | (b << 3);
    }
  } else {
    #pragma unroll
    for (int j = 3; j >= 0; --j){
      int l = (int)((IPI_TAB[(j + 1) & 3] >> (4 * s)) & 15);
      unsigned hw = __shfl(wlo, base + l);
      int b = (hw >> j) & 1;
      s = (s >> 1) | (b << 3);
    }
  }
  map[(size_t)pair * 16 + e] = (unsigned char)s;
}

// ---------------- K4: compose maps backward -> chunk end states ----------------
__global__ __launch_bounds__(256) void k_compose(const unsigned char* __restrict__ map,
                                                 unsigned char* __restrict__ Earr){
  const int seq = threadIdx.x;
  int s = 0;
  Earr[(size_t)NFULL * BB + seq] = 0;              // end state of tail chunk = 0
  #pragma unroll 4
  for (int c = NC - 1; c >= 1; --c){
    const uint4 mr = *(const uint4*)(map + ((size_t)c * BB + seq) * 16);
    unsigned wsel = (s < 8) ? ((s < 4) ? mr.x : mr.y) : ((s < 12) ? mr.z : mr.w);
    s = (wsel >> ((s & 3) * 8)) & 15;
    Earr[(size_t)(c - 1) * BB + seq] = (unsigned char)s;
  }
}

// ---------------- K5: re-trace from known end state, emit floats ----------------
__global__ __launch_bounds__(256) void k_emit(const unsigned long long* __restrict__ dec,
                                              const unsigned char* __restrict__ Earr,
                                              float* __restrict__ out){
  const int gt   = blockIdx.x * 256 + threadIdx.x;
  const int pair = gt >> 4;        // c*256+seq, c < 256
  const int l16  = gt & 15;
  const int c    = pair >> 8;
  const int seq  = pair & 255;
  const unsigned long long w = dec[(size_t)pair * 16 + l16];
  const unsigned wlo = (unsigned)w, whi = (unsigned)(w >> 32);
  const int base = (threadIdx.x & 63) & 48;
  int s = Earr[(size_t)c * BB + seq];
  float4 f = make_float4(0.f, 0.f, 0.f, 0.f);
  #pragma unroll
  for (int j = 63; j >= 0; --j){
    int l = (int)((IPI_TAB[(j + 1) & 3] >> (4 * s)) & 15);
    unsigned hw = __shfl((j >= 32) ? whi : wlo, base + l);
    int b = (hw >> (j & 31)) & 1;
    s = (s >> 1) | (b << 3);
    float fb = (float)b;           // output bit at n = 64*c + j
    if (l16 == (j >> 2)){
      if      ((j & 3) == 0) f.x = fb;
      else if ((j & 3) == 1) f.y = fb;
      else if ((j & 3) == 2) f.z = fb;
      else                   f.w = fb;
    }
  }
  *(float4*)(out + (size_t)seq * T_OUT + c * CHUNK + l16 * 4) = f;
}

extern "C" void kernel_launch(void* const* d_in, const int* in_sizes, int n_in,
                              void* d_out, int out_size, void* d_ws, size_t ws_size,
                              hipStream_t stream){
  const float* y = (const float*)d_in[0];
  const float* h = (const float*)d_in[1];
  float* out = (float*)d_out;

  const size_t CKPT_B = (size_t)NFULL * BB * 16 * 4;        // 4,194,304
  const size_t DEC_B  = (size_t)NC * BB * 16 * 8;           // 8,421,376
  const size_t MAP_B  = (size_t)NC * BB * 16;               // 1,052,672
  const size_t E_B    = (size_t)NC * BB;                    //    65,792
  if (ws_size < CKPT_B + DEC_B + MAP_B + E_B) return;

  char* ws = (char*)d_ws;
  float*              ckpt = (float*)ws;
  unsigned long long* dec  = (unsigned long long*)(ws + CKPT_B);
  unsigned char*      map  = (unsigned char*)(ws + CKPT_B + DEC_B);
  unsigned char*      Earr = (unsigned char*)(ws + CKPT_B + DEC_B + MAP_B);

  hipLaunchKernelGGL(k_forward, dim3(64),   dim3(64),  0, stream, y, h, ckpt);
  hipLaunchKernelGGL(k_replay,  dim3(4112), dim3(256), 0, stream, y, h, ckpt, dec);
  hipLaunchKernelGGL(k_maps,    dim3(4112), dim3(256), 0, stream, dec, map);
  hipLaunchKernelGGL(k_compose, dim3(1),    dim3(256), 0, stream, map, Earr);
  hipLaunchKernelGGL(k_emit,    dim3(4096), dim3(256), 0, stream, dec, Earr, out);
}

// Round 5
// 380.553 us; speedup vs baseline: 1.0551x; 1.0551x over previous
//
#include <hip/hip_runtime.h>

// Viterbi detector, bit-exact vs f32 reference.
// Lane-relabeled trellis: lane l holds state pi_phi(l), phase phi = t&3.
// Labelings are GF(2)-linear, chosen so the ACS partner exchange is a
// single-DPP pattern at EVERY phase: masks (8, 2, 1, 15) =
// row_ror:8 / quad_perm[2,3,0,1] / quad_perm[1,0,3,2] / row_mirror.
//   pi_0: s = (l2, l2^l0, l2^l1, l3^l2)   (bits s0..s3)
//   pi_1: s = (l3^l2, l2, l2^l0, l2^l1)
//   pi_2: s = (l2^l1, l3^l2, l2, l2^l0)
//   pi_3: s = (l2^l0, l2^l1, l3^l2, l2)
// K1 serial forward: fused v_min_f32_dpp chain; 2-chunk register prefetch
// pinned with sched_barrier(0) so the scheduler cannot sink the loads
// (R3/R4 showed it collapses the pipeline to <1 chunk otherwise).
// K2 parallel replay -> per-lane decision bits. K3 per-chunk traceback
// maps. K4 compose. K5 emit bits as floats.

#define DEV static __device__ __forceinline__

static constexpr int T_OUT = 16384;   // output bits per seq
static constexpr int TT    = 16388;   // T + MEM steps
static constexpr int BB    = 256;     // batch
static constexpr int CHUNK = 64;
static constexpr int NFULL = 256;     // full 64-step chunks
static constexpr int NC    = 257;     // + 4-step tail chunk

// inverse labelings, nibble-packed: lane = (IPI_TAB[phi] >> (4*s)) & 15
static constexpr unsigned long long IPI_TAB[4] = {
  0x4b5a6978c3d2e1f0ULL,   // pi_0^-1
  0x4cb35da26e917f80ULL,   // pi_1^-1
  0x46ceb93157dfa820ULL,   // pi_2^-1
  0x4567cdefba983210ULL,   // pi_3^-1
};

DEV int pi_of(int phi, int l){
  int l0=l&1, l1=(l>>1)&1, l2=(l>>2)&1, l3=(l>>3)&1;
  switch(phi & 3){
    case 0:  return (l2)      | ((l2^l0)<<1) | ((l2^l1)<<2) | ((l3^l2)<<3);
    case 1:  return (l3^l2)   | ((l2)<<1)    | ((l2^l0)<<2) | ((l2^l1)<<3);
    case 2:  return (l2^l1)   | ((l3^l2)<<1) | ((l2)<<2)    | ((l2^l0)<<3);
    default: return (l2^l0)   | ((l2^l1)<<1) | ((l3^l2)<<2) | ((l2)<<3);
  }
}

template<int CTRL>
DEV float dppmov(float x){
  return __int_as_float(__builtin_amdgcn_update_dpp(0, __float_as_int(x), CTRL, 0xF, 0xF, true));
}

// partner exchange per phase: masks 8, 2, 1, 15 (all single DPP)
template<int PH>
DEV float partner_of(float p){
  if constexpr (PH == 0) return dppmov<0x128>(p);   // row_ror:8      -> ^8
  else if constexpr (PH == 1) return dppmov<0x4E>(p);    // quad[2,3,0,1] -> ^2
  else if constexpr (PH == 2) return dppmov<0xB1>(p);    // quad[1,0,3,2] -> ^1
  else return dppmov<0x140>(p);                          // row_mirror    -> ^15
}

// expected[s] = sum_j (1-2*bit_j(s)) * h[j], sequential f32 accumulation
DEV float exp_of_state(int s, float h0, float h1, float h2, float h3){
  float e =            ((s     ) & 1) ? -h0 : h0;
  e = __fadd_rn(e, (((s >> 1)) & 1) ? -h1 : h1);
  e = __fadd_rn(e, (((s >> 2)) & 1) ? -h2 : h2);
  e = __fadd_rn(e, (((s >> 3)) & 1) ? -h3 : h3);
  return e;
}

// one ACS step, fused DPP-min chain: p = min(p, dpp(p)) + (y-E)^2
// s_nop 1 guards the (VALU writes p) -> (DPP reads p) hazard.
template<int PH>
DEV void vstep_fast(float& p, float yv, float E){
  float d    = __fsub_rn(yv, E);
  float cost = __fmul_rn(d, d);
  float mn;
  if constexpr (PH == 0)
    asm("s_nop 1\n\tv_min_f32_dpp %0, %1, %2 row_ror:8 row_mask:0xf bank_mask:0xf"
        : "=&v"(mn) : "v"(p), "v"(p));
  else if constexpr (PH == 1)
    asm("s_nop 1\n\tv_min_f32_dpp %0, %1, %2 quad_perm:[2,3,0,1] row_mask:0xf bank_mask:0xf"
        : "=&v"(mn) : "v"(p), "v"(p));
  else if constexpr (PH == 2)
    asm("s_nop 1\n\tv_min_f32_dpp %0, %1, %2 quad_perm:[1,0,3,2] row_mask:0xf bank_mask:0xf"
        : "=&v"(mn) : "v"(p), "v"(p));
  else
    asm("s_nop 1\n\tv_min_f32_dpp %0, %1, %2 row_mirror row_mask:0xf bank_mask:0xf"
        : "=&v"(mn) : "v"(p), "v"(p));
  p = __fadd_rn(mn, cost);
}

// ---------------- K1: serial forward, checkpoints only ----------------
// (64,1): VGPR budget up to 512 so the 2-chunk float4 queue (~150 VGPR
// live) fits. sched_barrier(0) after each prefetch load pins the load
// issue 128 steps ahead of its use — without it the scheduler sinks the
// loads and the chain stalls on HBM latency (R3/R4: VALUBusy 1.9%).
__global__ __launch_bounds__(64, 1) void k_forward(const float* __restrict__ y,
                                                   const float* __restrict__ h,
                                                   float* __restrict__ ckpt){
  const int lane = threadIdx.x & 63;
  const int l16  = lane & 15;
  const int seq  = blockIdx.x * 4 + (lane >> 4);
  const float h0 = h[0], h1 = h[1], h2 = h[2], h3 = h[3];
  const float EA = exp_of_state(pi_of(1,l16), h0,h1,h2,h3);
  const float EB = exp_of_state(pi_of(2,l16), h0,h1,h2,h3);
  const float EC = exp_of_state(pi_of(3,l16), h0,h1,h2,h3);
  const float ED = exp_of_state(pi_of(0,l16), h0,h1,h2,h3);
  const int   st0 = pi_of(0, l16);
  const float* yrow = y + (size_t)seq * TT;

  // two-chunk-deep register prefetch (static indexing only)
  float4 qA[16], qB[16];
  #pragma unroll
  for (int g = 0; g < 16; ++g) qA[g] = *(const float4*)(yrow + 4*g);
  #pragma unroll
  for (int g = 0; g < 16; ++g) qB[g] = *(const float4*)(yrow + CHUNK + 4*g);

  float p = 0.0f;                     // in0 = zeros
  for (int b = 0; b < NFULL; b += 2){
    {
      const int nb = (b + 2 < NFULL) ? b + 2 : NFULL - 1;
      const float* yn = yrow + nb * CHUNK;
      #pragma unroll
      for (int g = 0; g < 16; ++g){
        float4 yv = qA[g];
        qA[g] = *(const float4*)(yn + 4*g);   // prefetch chunk b+2
        __builtin_amdgcn_sched_barrier(0);    // pin: load may not sink below
        vstep_fast<0>(p, yv.x, EA);
        vstep_fast<1>(p, yv.y, EB);
        vstep_fast<2>(p, yv.z, EC);
        vstep_fast<3>(p, yv.w, ED);
      }
      ckpt[((size_t)b * BB + seq) * 16 + st0] = p;
    }
    {
      const int nb = (b + 3 < NFULL) ? b + 3 : NFULL - 1;
      const float* yn = yrow + nb * CHUNK;
      #pragma unroll
      for (int g = 0; g < 16; ++g){
        float4 yv = qB[g];
        qB[g] = *(const float4*)(yn + 4*g);   // prefetch chunk b+3
        __builtin_amdgcn_sched_barrier(0);
        vstep_fast<0>(p, yv.x, EA);
        vstep_fast<1>(p, yv.y, EB);
        vstep_fast<2>(p, yv.z, EC);
        vstep_fast<3>(p, yv.w, ED);
      }
      ckpt[((size_t)(b + 1) * BB + seq) * 16 + st0] = p;
    }
  }
}

// ---------------- K2: parallel chunk replay -> per-lane decision bits ----------
// role = (in-state bit3) per phase; decision d = strict (cand_b1 < cand_b0).
template<int PH>
DEV unsigned rstep(float& p, float yv, float E, bool role){
  float partner = partner_of<PH>(p);
  float c1 = role ? p : partner;
  float c0 = role ? partner : p;
  unsigned d = (c1 < c0) ? 1u : 0u;
  float mn = fminf(p, partner);
  float dd = __fsub_rn(yv, E);
  p = __fadd_rn(mn, __fmul_rn(dd, dd));
  return d;
}

__global__ __launch_bounds__(256) void k_replay(const float* __restrict__ y,
                                                const float* __restrict__ h,
                                                const float* __restrict__ ckpt,
                                                unsigned long long* __restrict__ dec){
  const int gt   = blockIdx.x * 256 + threadIdx.x;
  const int pair = gt >> 4;              // c*256 + seq
  const int l16  = gt & 15;
  const int c    = pair >> 8;
  const int seq  = pair & 255;
  const float h0 = h[0], h1 = h[1], h2 = h[2], h3 = h[3];
  const float EA = exp_of_state(pi_of(1,l16), h0,h1,h2,h3);
  const float EB = exp_of_state(pi_of(2,l16), h0,h1,h2,h3);
  const float EC = exp_of_state(pi_of(3,l16), h0,h1,h2,h3);
  const float ED = exp_of_state(pi_of(0,l16), h0,h1,h2,h3);
  const bool r0 = (((l16>>3) ^ (l16>>2)) & 1) != 0;   // bit3 of pi_0(l)
  const bool r1 = (((l16>>2) ^ (l16>>1)) & 1) != 0;   // bit3 of pi_1(l)
  const bool r2 = (((l16>>2) ^  l16    ) & 1) != 0;   // bit3 of pi_2(l)
  const bool r3 = (( l16>>2)             & 1) != 0;   // bit3 of pi_3(l)
  const int  st0 = pi_of(0, l16);

  float p = (c == 0) ? 0.0f : ckpt[((size_t)(c - 1) * BB + seq) * 16 + st0];
  const float* yc = y + (size_t)seq * TT + c * CHUNK;
  unsigned lo = 0, hi = 0;

  if (c < NFULL){
    #pragma unroll
    for (int g = 0; g < 16; ++g){
      float4 yv = *(const float4*)(yc + 4*g);
      unsigned d0 = rstep<0>(p, yv.x, EA, r0);
      unsigned d1 = rstep<1>(p, yv.y, EB, r1);
      unsigned d2 = rstep<2>(p, yv.z, EC, r2);
      unsigned d3 = rstep<3>(p, yv.w, ED, r3);
      const int t = 4 * g;
      if (t < 32) lo |= (d0 << t) | (d1 << (t+1)) | (d2 << (t+2)) | (d3 << (t+3));
      else        hi |= (d0 << (t-32)) | (d1 << (t-31)) | (d2 << (t-30)) | (d3 << (t-29));
    }
  } else {
    float4 yv = *(const float4*)(yc);
    unsigned d0 = rstep<0>(p, yv.x, EA, r0);
    unsigned d1 = rstep<1>(p, yv.y, EB, r1);
    unsigned d2 = rstep<2>(p, yv.z, EC, r2);
    unsigned d3 = rstep<3>(p, yv.w, ED, r3);
    lo = d0 | (d1 << 1) | (d2 << 2) | (d3 << 3);
  }
  dec[(size_t)pair * 16 + l16] = ((unsigned long long)hi << 32) | lo;
}

// ---------------- K3: per-chunk 16-hypothesis traceback -> maps ----------------
__global__ __launch_bounds__(256) void k_maps(const unsigned long long* __restrict__ dec,
                                              unsigned char* __restrict__ map){
  const int gt   = blockIdx.x * 256 + threadIdx.x;
  const int pair = gt >> 4;
  const int e    = gt & 15;        // end-state hypothesis; also this lane's word index
  const int c    = pair >> 8;
  const unsigned long long w = dec[(size_t)pair * 16 + e];
  const unsigned wlo = (unsigned)w, whi = (unsigned)(w >> 32);
  const int base = (threadIdx.x & 63) & 48;
  int s = e;
  if (c < NFULL){
    #pragma unroll
    for (int j = 63; j >= 0; --j){
      int l = (int)((IPI_TAB[(j + 1) & 3] >> (4 * s)) & 15);
      unsigned hw = __shfl((j >= 32) ? whi : wlo, base + l);
      int b = (hw >> (j & 31)) & 1;
      s = (s >> 1) | (b << 3);
    }
  } else {
    #pragma unroll
    for (int j = 3; j >= 0; --j){
      int l = (int)((IPI_TAB[(j + 1) & 3] >> (4 * s)) & 15);
      unsigned hw = __shfl(wlo, base + l);
      int b = (hw >> j) & 1;
      s = (s >> 1) | (b << 3);
    }
  }
  map[(size_t)pair * 16 + e] = (unsigned char)s;
}

// ---------------- K4: compose maps backward -> chunk end states ----------------
__global__ __launch_bounds__(256) void k_compose(const unsigned char* __restrict__ map,
                                                 unsigned char* __restrict__ Earr){
  const int seq = threadIdx.x;
  int s = 0;
  Earr[(size_t)NFULL * BB + seq] = 0;              // end state of tail chunk = 0
  #pragma unroll 4
  for (int c = NC - 1; c >= 1; --c){
    const uint4 mr = *(const uint4*)(map + ((size_t)c * BB + seq) * 16);
    unsigned wsel = (s < 8) ? ((s < 4) ? mr.x : mr.y) : ((s < 12) ? mr.z : mr.w);
    s = (wsel >> ((s & 3) * 8)) & 15;
    Earr[(size_t)(c - 1) * BB + seq] = (unsigned char)s;
  }
}

// ---------------- K5: re-trace from known end state, emit floats ----------------
__global__ __launch_bounds__(256) void k_emit(const unsigned long long* __restrict__ dec,
                                              const unsigned char* __restrict__ Earr,
                                              float* __restrict__ out){
  const int gt   = blockIdx.x * 256 + threadIdx.x;
  const int pair = gt >> 4;        // c*256+seq, c < 256
  const int l16  = gt & 15;
  const int c    = pair >> 8;
  const int seq  = pair & 255;
  const unsigned long long w = dec[(size_t)pair * 16 + l16];
  const unsigned wlo = (unsigned)w, whi = (unsigned)(w >> 32);
  const int base = (threadIdx.x & 63) & 48;
  int s = Earr[(size_t)c * BB + seq];
  float4 f = make_float4(0.f, 0.f, 0.f, 0.f);
  #pragma unroll
  for (int j = 63; j >= 0; --j){
    int l = (int)((IPI_TAB[(j + 1) & 3] >> (4 * s)) & 15);
    unsigned hw = __shfl((j >= 32) ? whi : wlo, base + l);
    int b = (hw >> (j & 31)) & 1;
    s = (s >> 1) | (b << 3);
    float fb = (float)b;           // output bit at n = 64*c + j
    if (l16 == (j >> 2)){
      if      ((j & 3) == 0) f.x = fb;
      else if ((j & 3) == 1) f.y = fb;
      else if ((j & 3) == 2) f.z = fb;
      else                   f.w = fb;
    }
  }
  *(float4*)(out + (size_t)seq * T_OUT + c * CHUNK + l16 * 4) = f;
}

extern "C" void kernel_launch(void* const* d_in, const int* in_sizes, int n_in,
                              void* d_out, int out_size, void* d_ws, size_t ws_size,
                              hipStream_t stream){
  const float* y = (const float*)d_in[0];
  const float* h = (const float*)d_in[1];
  float* out = (float*)d_out;

  const size_t CKPT_B = (size_t)NFULL * BB * 16 * 4;        // 4,194,304
  const size_t DEC_B  = (size_t)NC * BB * 16 * 8;           // 8,421,376
  const size_t MAP_B  = (size_t)NC * BB * 16;               // 1,052,672
  const size_t E_B    = (size_t)NC * BB;                    //    65,792
  if (ws_size < CKPT_B + DEC_B + MAP_B + E_B) return;

  char* ws = (char*)d_ws;
  float*              ckpt = (float*)ws;
  unsigned long long* dec  = (unsigned long long*)(ws + CKPT_B);
  unsigned char*      map  = (unsigned char*)(ws + CKPT_B + DEC_B);
  unsigned char*      Earr = (unsigned char*)(ws + CKPT_B + DEC_B + MAP_B);

  hipLaunchKernelGGL(k_forward, dim3(64),   dim3(64),  0, stream, y, h, ckpt);
  hipLaunchKernelGGL(k_replay,  dim3(4112), dim3(256), 0, stream, y, h, ckpt, dec);
  hipLaunchKernelGGL(k_maps,    dim3(4112), dim3(256), 0, stream, dec, map);
  hipLaunchKernelGGL(k_compose, dim3(1),    dim3(256), 0, stream, map, Earr);
  hipLaunchKernelGGL(k_emit,    dim3(4096), dim3(256), 0, stream, dec, Earr, out);
}